// Round 6
// baseline (259.628 us; speedup 1.0000x reference)
//
#include <hip/hip_runtime.h>

#define A     96
#define DET0  256
#define NZ    32
#define NY    256
#define NX    256
#define T     256
#define LAMB  0.01f

// ws layout (floats):
//   trig  : [A][2]            @ 0        (192, padded to 256)
//   res_t : [A][DET0][NZ]     @ 256      (786,432)
//   vol_t : [NY][NX][NZ] fp32 @ 786,688  (2,097,152)
//   part  : [P][A][DET0][NZ]  @ 2,883,840  (P <= 4)
#define TRIG_OFF  0
#define REST_OFF  256
#define VOLT_OFF  786688
#define PART_OFF  2883840
#define RES_ELEMS 786432

// ---------------------------------------------------------------------------
// K1: transpose vol (z,y,x) -> vol_t (y,x,z) fp32; fill trig table.
// grid (NX/64, NY), block 256
__global__ __launch_bounds__(256) void k_transpose(const float* __restrict__ src,
                                                   float* __restrict__ vol_t,
                                                   float* __restrict__ trig) {
    __shared__ float lds[64 * 33];
    const int y   = blockIdx.y;
    const int x0  = blockIdx.x * 64;
    const int tid = threadIdx.x;

    if (blockIdx.x == 0 && y == 0 && tid < A) {
        float th = (float)tid * (float)(3.14159265358979323846 / (double)A);
        trig[2 * tid]     = cosf(th);
        trig[2 * tid + 1] = sinf(th);
    }

    const int xr = tid & 63;
    const int zr = tid >> 6;  // 0..3
    #pragma unroll
    for (int pz = 0; pz < 8; ++pz) {
        int z = pz * 4 + zr;
        lds[xr * 33 + z] = src[(z * NY + y) * NX + x0 + xr];
    }
    __syncthreads();
    const int zw = tid & 31;
    const int xw = tid >> 5;  // 0..7
    #pragma unroll
    for (int px = 0; px < 8; ++px) {
        int xi = px * 8 + xw;
        vol_t[(size_t)(y * NX + x0 + xi) * NZ + zw] = lds[xi * 33 + zw];
    }
}

// ---------------------------------------------------------------------------
__device__ __forceinline__ void acc8f(float* acc, float4 qa, float4 qb, float w) {
    acc[0] = fmaf(w, qa.x, acc[0]); acc[1] = fmaf(w, qa.y, acc[1]);
    acc[2] = fmaf(w, qa.z, acc[2]); acc[3] = fmaf(w, qa.w, acc[3]);
    acc[4] = fmaf(w, qb.x, acc[4]); acc[5] = fmaf(w, qb.y, acc[5]);
    acc[6] = fmaf(w, qb.z, acc[6]); acc[7] = fmaf(w, qb.w, acc[7]);
}

// t-range helper: solve L <= t*g + b <= H for t (tt = t - 127.5 domain)
__device__ __forceinline__ void rng(float g, float b, float L, float H,
                                    float& lo, float& hi) {
    if (fabsf(g) > 1e-5f) {
        float r0 = (L - b) / g, r1 = (H - b) / g;
        lo = fminf(r0, r1); hi = fmaxf(r0, r1);
    } else {
        bool in = (b >= L && b <= H);
        lo = in ? -1e9f : 1e9f;
        hi = in ? 1e9f : -1e9f;
    }
}
__device__ __forceinline__ int clampi(float v) {
    return (int)fminf(fmaxf(v, -2.f), 258.f);
}

// fully-masked edge sample (boundary t's), fp32 volume
__device__ __forceinline__ void sample_edge(const char* base, float ix, float iy,
                                            float* acc) {
    float xf = floorf(ix), yf = floorf(iy);
    float fx = ix - xf, fy = iy - yf;
    int x0 = (int)xf, y0 = (int)yf;
    float wx0 = 1.f - fx, wx1 = fx, wy0 = 1.f - fy, wy1 = fy;
    if ((unsigned)x0 >= NX)       wx0 = 0.f;
    if ((unsigned)(x0 + 1) >= NX) wx1 = 0.f;
    if ((unsigned)y0 >= NY)       wy0 = 0.f;
    if ((unsigned)(y0 + 1) >= NY) wy1 = 0.f;
    if ((wx0 == 0.f && wx1 == 0.f) || (wy0 == 0.f && wy1 == 0.f)) return;
    int cx0 = min(max(x0, 0), NX - 1);
    int cx1 = min(max(x0 + 1, 0), NX - 1);
    int cy0 = min(max(y0, 0), NY - 1);
    int cy1 = min(max(y0 + 1, 0), NY - 1);
    const char* p00 = base + ((size_t)((cy0 << 8) + cx0) << 7);
    const char* p01 = base + ((size_t)((cy0 << 8) + cx1) << 7);
    const char* p10 = base + ((size_t)((cy1 << 8) + cx0) << 7);
    const char* p11 = base + ((size_t)((cy1 << 8) + cx1) << 7);
    acc8f(acc, *(const float4*)p00, *(const float4*)(p00 + 16), wy0 * wx0);
    acc8f(acc, *(const float4*)p01, *(const float4*)(p01 + 16), wy0 * wx1);
    acc8f(acc, *(const float4*)p10, *(const float4*)(p10 + 16), wy1 * wx0);
    acc8f(acc, *(const float4*)p11, *(const float4*)(p11 + 16), wy1 * wx1);
}

// ---------------------------------------------------------------------------
// K3: forward projection. thread = (u, z-quarter of 8). Each block handles
// paired t-windows {w, 7-w} (balanced load). 1D grid, angle fastest.
// grid (4 * P * A), block 256
__global__ __launch_bounds__(256, 4) void k_forward(const float* __restrict__ vol_t,
                                                    const float* __restrict__ trig,
                                                    float* __restrict__ part,
                                                    int P) {
    const unsigned bid = blockIdx.x;
    const unsigned a   = bid % (unsigned)A;
    const unsigned r   = bid / (unsigned)A;
    const unsigned pr  = r % (unsigned)P;
    const unsigned ug  = r / (unsigned)P;
    const int tid = threadIdx.x;
    const int u  = ug * 64 + (tid >> 2);
    const int zq = tid & 3;                 // 8 z per lane (8 fp32 = 32 bytes)

    const float c = trig[2 * a];
    const float s = trig[2 * a + 1];
    const float uu = (float)u - 127.5f;
    const float bx = fmaf(-uu, s, 127.5f);  // ix = tt*c + bx
    const float by = fmaf(uu, c, 127.5f);   // iy = tt*s + by

    // global full/interior t-ranges for this u
    float lo1, hi1, lo2, hi2;
    rng(c, bx, -1.f, 256.f, lo1, hi1);
    rng(s, by, -1.f, 256.f, lo2, hi2);
    float fl = fmaxf(lo1, lo2), fh = fminf(hi1, hi2);
    const int gF0 = clampi(ceilf(fl + 127.5f));
    const int gF1 = clampi(floorf(fh + 127.5f));
    rng(c, bx, 1.f, 253.5f, lo1, hi1);
    rng(s, by, 1.f, 253.5f, lo2, hi2);
    float il = fmaxf(lo1, lo2), ih = fminf(hi1, hi2);
    const int gI0 = clampi(ceilf(il + 127.5f)) + 1;
    const int gI1 = clampi(floorf(ih + 127.5f)) - 1;

    const char* base = (const char*)vol_t + zq * 32;   // FIXED: fp32 z-stride
    float acc[8];
    #pragma unroll
    for (int k = 0; k < 8; ++k) acc[k] = 0.f;

    for (int wi = (int)pr; wi < 4; wi += P) {
        #pragma unroll
        for (int side = 0; side < 2; ++side) {
            int w = side ? (7 - wi) : wi;
            int tF0 = max(w * 32, gF0);
            int tF1 = min(w * 32 + 31, gF1);
            int tI0 = max(gI0, tF0);
            int tI1 = min(gI1, tF1);
            if (tI0 > tI1) { tI0 = tF1 + 1; tI1 = tF1; }

            for (int t = tF0; t < tI0; ++t) {
                float ttf = (float)t - 127.5f;
                sample_edge(base, fmaf(ttf, c, bx), fmaf(ttf, s, by), acc);
            }
            for (int t = tI0; t <= tI1; ++t) {
                float ttf = (float)t - 127.5f;
                float ix = fmaf(ttf, c, bx);
                float iy = fmaf(ttf, s, by);
                float xf = floorf(ix), yf = floorf(iy);
                float fx = ix - xf, fy = iy - yf;
                int row = ((int)yf << 8) + (int)xf;
                const char* p0 = base + ((size_t)row << 7);
                float4 a00 = *(const float4*)(p0);
                float4 b00 = *(const float4*)(p0 + 16);
                float4 a01 = *(const float4*)(p0 + 128);
                float4 b01 = *(const float4*)(p0 + 144);
                float4 a10 = *(const float4*)(p0 + 32768);
                float4 b10 = *(const float4*)(p0 + 32784);
                float4 a11 = *(const float4*)(p0 + 32896);
                float4 b11 = *(const float4*)(p0 + 32912);
                float wx0 = 1.f - fx, wy0 = 1.f - fy;
                acc8f(acc, a00, b00, wy0 * wx0);
                acc8f(acc, a01, b01, wy0 * fx);
                acc8f(acc, a10, b10, fy * wx0);
                acc8f(acc, a11, b11, fy * fx);
            }
            for (int t = tI1 + 1; t <= tF1; ++t) {
                float ttf = (float)t - 127.5f;
                sample_edge(base, fmaf(ttf, c, bx), fmaf(ttf, s, by), acc);
            }
        }
    }

    float4* dst = (float4*)(part + (size_t)pr * RES_ELEMS +
                            (((int)a * DET0 + u) * NZ + zq * 8));
    dst[0] = make_float4(acc[0], acc[1], acc[2], acc[3]);
    dst[1] = make_float4(acc[4], acc[5], acc[6], acc[7]);
}

// ---------------------------------------------------------------------------
// K3b: res_t = -p_perm + sum_c part[c].  grid (A, 4), block 256
__global__ __launch_bounds__(256) void k_combine(const float* __restrict__ p,
                                                 const float* __restrict__ part,
                                                 float* __restrict__ res_t,
                                                 int P) {
    __shared__ float lds[64 * 33];
    const int a  = blockIdx.x;
    const int uq = blockIdx.y;
    const int tid = threadIdx.x;
    #pragma unroll
    for (int k = 0; k < 8; ++k) {
        int e  = k * 256 + tid;  // 0..2047
        int uo = e & 63;
        int z  = e >> 6;
        int pidx = a * 8192 + (((z & 7) << 2) + (z >> 3)) * 256 + uq * 64 + uo;
        lds[uo * 33 + z] = p[pidx];
    }
    __syncthreads();
    #pragma unroll
    for (int k = 0; k < 2; ++k) {
        int j4 = k * 256 + tid;          // float4 index within (a,uq)
        int uo = j4 >> 3;
        int zb = (j4 & 7) * 4;
        float4 v = make_float4(-lds[uo * 33 + zb],     -lds[uo * 33 + zb + 1],
                               -lds[uo * 33 + zb + 2], -lds[uo * 33 + zb + 3]);
        size_t gi = (size_t)a * 2048 + uq * 512 + j4;
        for (int c = 0; c < P; ++c) {
            float4 w = ((const float4*)(part + (size_t)c * RES_ELEMS))[gi];
            v.x += w.x; v.y += w.y; v.z += w.z; v.w += w.w;
        }
        ((float4*)res_t)[gi] = v;
    }
}

// ---------------------------------------------------------------------------
// K4: backprojection, y-tiled x4. thread = (x, z-quarter of 4), 4 y-accums.
// Inline weights via ub recurrence; res_t rows reused across y through L1.
// grid (NX/32, NY/4), block 256
__global__ __launch_bounds__(256) void k_backward(const float* __restrict__ res_t,
                                                  const float* __restrict__ trig,
                                                  float* __restrict__ out) {
    __shared__ float ob[32 * 33];
    const int tid = threadIdx.x;
    const int xs = tid >> 3;         // 0..31
    const int zq = tid & 7;          // 4 z per lane
    const int xb = blockIdx.x * 32;
    const int yb = blockIdx.y * 4;
    const float xx = (float)(xb + xs) - 127.5f;
    const float yy = (float)yb - 127.5f;

    float4 acc[4];
    #pragma unroll
    for (int k = 0; k < 4; ++k) acc[k] = make_float4(0.f, 0.f, 0.f, 0.f);

    const char* rbase = (const char*)res_t + zq * 16;
    for (int a = 0; a < A; ++a) {
        float cc = trig[2 * a];
        float ss = trig[2 * a + 1];
        float ub = fmaf(-xx, ss, fmaf(yy, cc, 127.5f));
        int abase = a * DET0;
        #pragma unroll
        for (int y = 0; y < 4; ++y) {
            float uf = floorf(ub);
            float fu = ub - uf;
            int i0 = (int)uf;
            float w0 = ((unsigned)i0 < 256u) ? (1.f - fu) : 0.f;
            float w1 = ((unsigned)(i0 + 1) < 256u) ? fu : 0.f;
            int c0 = min(max(i0, 0), 255);
            int c1 = min(max(i0 + 1, 0), 255);
            float4 v0 = *(const float4*)(rbase + ((size_t)(abase + c0) << 7));
            float4 v1 = *(const float4*)(rbase + ((size_t)(abase + c1) << 7));
            acc[y].x = fmaf(w0, v0.x, fmaf(w1, v1.x, acc[y].x));
            acc[y].y = fmaf(w0, v0.y, fmaf(w1, v1.y, acc[y].y));
            acc[y].z = fmaf(w0, v0.z, fmaf(w1, v1.z, acc[y].z));
            acc[y].w = fmaf(w0, v0.w, fmaf(w1, v1.w, acc[y].w));
            ub += cc;
        }
    }

    #pragma unroll
    for (int y = 0; y < 4; ++y) {
        __syncthreads();
        ob[(zq * 4 + 0) * 33 + xs] = acc[y].x;
        ob[(zq * 4 + 1) * 33 + xs] = acc[y].y;
        ob[(zq * 4 + 2) * 33 + xs] = acc[y].z;
        ob[(zq * 4 + 3) * 33 + xs] = acc[y].w;
        __syncthreads();
        int z  = tid >> 3;
        int x4 = (tid & 7) * 4;
        float4 o = make_float4(ob[z * 33 + x4],     ob[z * 33 + x4 + 1],
                               ob[z * 33 + x4 + 2], ob[z * 33 + x4 + 3]);
        *(float4*)(out + (size_t)z * (NY * NX) + (yb + y) * NX + xb + x4) =
            make_float4(-LAMB * o.x, -LAMB * o.y, -LAMB * o.z, -LAMB * o.w);
    }
}

// ---------------------------------------------------------------------------
extern "C" void kernel_launch(void* const* d_in, const int* in_sizes, int n_in,
                              void* d_out, int out_size, void* d_ws, size_t ws_size,
                              hipStream_t stream) {
    const float* x = (const float*)d_in[0];   // (1,1,32,256,256)
    const float* p = (const float*)d_in[1];   // (1,1,384,8,256)
    float* out = (float*)d_out;               // (1,1,32,256,256)
    float* ws  = (float*)d_ws;

    float* trig  = ws + TRIG_OFF;
    float* res_t = ws + REST_OFF;
    float* vol_t = ws + VOLT_OFF;
    float* part  = ws + PART_OFF;

    // largest power-of-2 pair count whose partials fit in ws (expect 4)
    size_t avail = ws_size / 4;
    int P = 4;
    while (P > 1 && (size_t)PART_OFF + (size_t)P * RES_ELEMS > avail) P >>= 1;

    k_transpose<<<dim3(NX / 64, NY), 256, 0, stream>>>(x, vol_t, trig);
    k_forward  <<<dim3(4 * P * A), 256, 0, stream>>>(vol_t, trig, part, P);
    k_combine  <<<dim3(A, 4), 256, 0, stream>>>(p, part, res_t, P);
    k_backward <<<dim3(NX / 32, NY / 4), 256, 0, stream>>>(res_t, trig, out);
}

// Round 7
// 237.606 us; speedup vs baseline: 1.0927x; 1.0927x over previous
//
#include <hip/hip_runtime.h>

#define A     96
#define DET0  256
#define NZ    32
#define NY    256
#define NX    256
#define T     256
#define LAMB  0.01f

// ws layout (floats):
//   trig  : [A][2]            @ 0        (192, padded to 256)
//   res_t : [A][DET0][NZ]     @ 256      (786,432)
//   vol_b : [NY][NX][NZ] bf16 @ 786,688  (2,097,152 ushort = 1,048,576 floats)
//   part  : [P][A][DET0][NZ]  @ 1,835,264  (P <= 2)
#define TRIG_OFF  0
#define REST_OFF  256
#define VOLB_OFF  786688
#define PART_OFF  1835264
#define RES_ELEMS 786432

__device__ __forceinline__ unsigned short f2bf_rne(float f) {
    unsigned u = __float_as_uint(f);
    unsigned r = u + 0x7FFF + ((u >> 16) & 1);
    return (unsigned short)(r >> 16);
}
__device__ __forceinline__ float blo(unsigned u) { return __uint_as_float(u << 16); }
__device__ __forceinline__ float bhi(unsigned u) { return __uint_as_float(u & 0xFFFF0000u); }

// accumulate 8 bf16 (one vol row segment) * w into acc[0..7]
__device__ __forceinline__ void acc8(float* acc, uint4 q, float w) {
    acc[0] = fmaf(w, blo(q.x), acc[0]); acc[1] = fmaf(w, bhi(q.x), acc[1]);
    acc[2] = fmaf(w, blo(q.y), acc[2]); acc[3] = fmaf(w, bhi(q.y), acc[3]);
    acc[4] = fmaf(w, blo(q.z), acc[4]); acc[5] = fmaf(w, bhi(q.z), acc[5]);
    acc[6] = fmaf(w, blo(q.w), acc[6]); acc[7] = fmaf(w, bhi(q.w), acc[7]);
}

// ---------------------------------------------------------------------------
// K1: transpose vol (z,y,x) fp32 -> vol_b (y,x,z) bf16; fill trig table.
// grid (NX/64, NY), block 256
__global__ __launch_bounds__(256) void k_transpose(const float* __restrict__ src,
                                                   unsigned short* __restrict__ vol_b,
                                                   float* __restrict__ trig) {
    __shared__ float lds[64 * 33];
    const int y   = blockIdx.y;
    const int x0  = blockIdx.x * 64;
    const int tid = threadIdx.x;

    if (blockIdx.x == 0 && y == 0 && tid < A) {
        float th = (float)tid * (float)(3.14159265358979323846 / (double)A);
        trig[2 * tid]     = cosf(th);
        trig[2 * tid + 1] = sinf(th);
    }

    const int xr = tid & 63;
    const int zr = tid >> 6;  // 0..3
    #pragma unroll
    for (int pz = 0; pz < 8; ++pz) {
        int z = pz * 4 + zr;
        lds[xr * 33 + z] = src[(z * NY + y) * NX + x0 + xr];
    }
    __syncthreads();
    const int zw = tid & 31;
    const int xw = tid >> 5;  // 0..7
    #pragma unroll
    for (int px = 0; px < 8; ++px) {
        int xi = px * 8 + xw;
        vol_b[(y * NX + x0 + xi) * NZ + zw] = f2bf_rne(lds[xi * 33 + zw]);
    }
}

// ---------------------------------------------------------------------------
// t-range helper: solve L <= t*g + b <= H for t (tt = t - 127.5 domain)
__device__ __forceinline__ void rng(float g, float b, float L, float H,
                                    float& lo, float& hi) {
    if (fabsf(g) > 1e-5f) {
        float r0 = (L - b) / g, r1 = (H - b) / g;
        lo = fminf(r0, r1); hi = fmaxf(r0, r1);
    } else {
        bool in = (b >= L && b <= H);
        lo = in ? -1e9f : 1e9f;
        hi = in ? 1e9f : -1e9f;
    }
}
__device__ __forceinline__ int clampi(float v) {
    return (int)fminf(fmaxf(v, -2.f), 258.f);
}

// fully-masked edge sample (boundary t's), bf16 volume
__device__ __forceinline__ void sample_edge(const char* base, float ix, float iy,
                                            float* acc) {
    float xf = floorf(ix), yf = floorf(iy);
    float fx = ix - xf, fy = iy - yf;
    int x0 = (int)xf, y0 = (int)yf;
    float wx0 = 1.f - fx, wx1 = fx, wy0 = 1.f - fy, wy1 = fy;
    if ((unsigned)x0 >= NX)       wx0 = 0.f;
    if ((unsigned)(x0 + 1) >= NX) wx1 = 0.f;
    if ((unsigned)y0 >= NY)       wy0 = 0.f;
    if ((unsigned)(y0 + 1) >= NY) wy1 = 0.f;
    if ((wx0 == 0.f && wx1 == 0.f) || (wy0 == 0.f && wy1 == 0.f)) return;
    int cx0 = min(max(x0, 0), NX - 1);
    int cx1 = min(max(x0 + 1, 0), NX - 1);
    int cy0 = min(max(y0, 0), NY - 1);
    int cy1 = min(max(y0 + 1, 0), NY - 1);
    uint4 q00 = *(const uint4*)(base + ((size_t)((cy0 << 8) + cx0) << 6));
    uint4 q01 = *(const uint4*)(base + ((size_t)((cy0 << 8) + cx1) << 6));
    uint4 q10 = *(const uint4*)(base + ((size_t)((cy1 << 8) + cx0) << 6));
    uint4 q11 = *(const uint4*)(base + ((size_t)((cy1 << 8) + cx1) << 6));
    acc8(acc, q00, wy0 * wx0);
    acc8(acc, q01, wy0 * wx1);
    acc8(acc, q10, wy1 * wx0);
    acc8(acc, q11, wy1 * wx1);
}

// ---------------------------------------------------------------------------
// K3: forward projection, bf16 volume. thread = (u, z-quarter of 8).
// Each block handles window pairs {wi, 7-wi} for wi = pr, pr+P (balanced).
// 1D grid, angle fastest.  grid (4 * P * A), block 256
__global__ __launch_bounds__(256) void k_forward(const unsigned short* __restrict__ vol_b,
                                                 const float* __restrict__ trig,
                                                 float* __restrict__ part,
                                                 int P) {
    const unsigned bid = blockIdx.x;
    const unsigned a   = bid % (unsigned)A;
    const unsigned r   = bid / (unsigned)A;
    const unsigned pr  = r % (unsigned)P;
    const unsigned ug  = r / (unsigned)P;
    const int tid = threadIdx.x;
    const int u  = ug * 64 + (tid >> 2);
    const int zq = tid & 3;                 // 8 bf16 z per lane = 16 bytes

    const float c = trig[2 * a];
    const float s = trig[2 * a + 1];
    const float uu = (float)u - 127.5f;
    const float bx = fmaf(-uu, s, 127.5f);  // ix = tt*c + bx
    const float by = fmaf(uu, c, 127.5f);   // iy = tt*s + by

    // global full/interior t-ranges for this u
    float lo1, hi1, lo2, hi2;
    rng(c, bx, -1.f, 256.f, lo1, hi1);
    rng(s, by, -1.f, 256.f, lo2, hi2);
    float fl = fmaxf(lo1, lo2), fh = fminf(hi1, hi2);
    const int gF0 = clampi(ceilf(fl + 127.5f));
    const int gF1 = clampi(floorf(fh + 127.5f));
    rng(c, bx, 1.f, 253.5f, lo1, hi1);
    rng(s, by, 1.f, 253.5f, lo2, hi2);
    float il = fmaxf(lo1, lo2), ih = fminf(hi1, hi2);
    const int gI0 = clampi(ceilf(il + 127.5f)) + 1;
    const int gI1 = clampi(floorf(ih + 127.5f)) - 1;

    const char* base = (const char*)vol_b + zq * 16;
    float acc[8];
    #pragma unroll
    for (int k = 0; k < 8; ++k) acc[k] = 0.f;

    for (int wi = (int)pr; wi < 4; wi += P) {
        #pragma unroll
        for (int side = 0; side < 2; ++side) {
            int w = side ? (7 - wi) : wi;
            int tF0 = max(w * 32, gF0);
            int tF1 = min(w * 32 + 31, gF1);
            int tI0 = max(gI0, tF0);
            int tI1 = min(gI1, tF1);
            if (tI0 > tI1) { tI0 = tF1 + 1; tI1 = tF1; }

            for (int t = tF0; t < tI0; ++t) {
                float ttf = (float)t - 127.5f;
                sample_edge(base, fmaf(ttf, c, bx), fmaf(ttf, s, by), acc);
            }
            for (int t = tI0; t <= tI1; ++t) {
                float ttf = (float)t - 127.5f;
                float ix = fmaf(ttf, c, bx);
                float iy = fmaf(ttf, s, by);
                float xf = floorf(ix), yf = floorf(iy);
                float fx = ix - xf, fy = iy - yf;
                int row = ((int)yf << 8) + (int)xf;
                const char* p0 = base + ((size_t)row << 6);
                uint4 q00 = *(const uint4*)(p0);
                uint4 q01 = *(const uint4*)(p0 + 64);
                uint4 q10 = *(const uint4*)(p0 + 16384);
                uint4 q11 = *(const uint4*)(p0 + 16384 + 64);
                float wx0 = 1.f - fx, wy0 = 1.f - fy;
                acc8(acc, q00, wy0 * wx0);
                acc8(acc, q01, wy0 * fx);
                acc8(acc, q10, fy * wx0);
                acc8(acc, q11, fy * fx);
            }
            for (int t = tI1 + 1; t <= tF1; ++t) {
                float ttf = (float)t - 127.5f;
                sample_edge(base, fmaf(ttf, c, bx), fmaf(ttf, s, by), acc);
            }
        }
    }

    float4* dst = (float4*)(part + (size_t)pr * RES_ELEMS +
                            (((int)a * DET0 + u) * NZ + zq * 8));
    dst[0] = make_float4(acc[0], acc[1], acc[2], acc[3]);
    dst[1] = make_float4(acc[4], acc[5], acc[6], acc[7]);
}

// ---------------------------------------------------------------------------
// K3b: res_t = -p_perm + sum_c part[c].  grid (A, 4), block 256
__global__ __launch_bounds__(256) void k_combine(const float* __restrict__ p,
                                                 const float* __restrict__ part,
                                                 float* __restrict__ res_t,
                                                 int P) {
    __shared__ float lds[64 * 33];
    const int a  = blockIdx.x;
    const int uq = blockIdx.y;
    const int tid = threadIdx.x;
    #pragma unroll
    for (int k = 0; k < 8; ++k) {
        int e  = k * 256 + tid;  // 0..2047
        int uo = e & 63;
        int z  = e >> 6;
        int pidx = a * 8192 + (((z & 7) << 2) + (z >> 3)) * 256 + uq * 64 + uo;
        lds[uo * 33 + z] = p[pidx];
    }
    __syncthreads();
    #pragma unroll
    for (int k = 0; k < 2; ++k) {
        int j4 = k * 256 + tid;          // float4 index within (a,uq)
        int uo = j4 >> 3;
        int zb = (j4 & 7) * 4;
        float4 v = make_float4(-lds[uo * 33 + zb],     -lds[uo * 33 + zb + 1],
                               -lds[uo * 33 + zb + 2], -lds[uo * 33 + zb + 3]);
        size_t gi = (size_t)a * 2048 + uq * 512 + j4;
        for (int c = 0; c < P; ++c) {
            float4 w = ((const float4*)(part + (size_t)c * RES_ELEMS))[gi];
            v.x += w.x; v.y += w.y; v.z += w.z; v.w += w.w;
        }
        ((float4*)res_t)[gi] = v;
    }
}

// ---------------------------------------------------------------------------
// K4: backprojection, y-tiled x4. thread = (x, z-quarter of 4), 4 y-accums.
// grid (NX/32, NY/4), block 256
__global__ __launch_bounds__(256) void k_backward(const float* __restrict__ res_t,
                                                  const float* __restrict__ trig,
                                                  float* __restrict__ out) {
    __shared__ float ob[32 * 33];
    const int tid = threadIdx.x;
    const int xs = tid >> 3;         // 0..31
    const int zq = tid & 7;          // 4 z per lane
    const int xb = blockIdx.x * 32;
    const int yb = blockIdx.y * 4;
    const float xx = (float)(xb + xs) - 127.5f;
    const float yy = (float)yb - 127.5f;

    float4 acc[4];
    #pragma unroll
    for (int k = 0; k < 4; ++k) acc[k] = make_float4(0.f, 0.f, 0.f, 0.f);

    const char* rbase = (const char*)res_t + zq * 16;
    for (int a = 0; a < A; ++a) {
        float cc = trig[2 * a];
        float ss = trig[2 * a + 1];
        float ub = fmaf(-xx, ss, fmaf(yy, cc, 127.5f));
        int abase = a * DET0;
        #pragma unroll
        for (int y = 0; y < 4; ++y) {
            float uf = floorf(ub);
            float fu = ub - uf;
            int i0 = (int)uf;
            float w0 = ((unsigned)i0 < 256u) ? (1.f - fu) : 0.f;
            float w1 = ((unsigned)(i0 + 1) < 256u) ? fu : 0.f;
            int c0 = min(max(i0, 0), 255);
            int c1 = min(max(i0 + 1, 0), 255);
            float4 v0 = *(const float4*)(rbase + ((size_t)(abase + c0) << 7));
            float4 v1 = *(const float4*)(rbase + ((size_t)(abase + c1) << 7));
            acc[y].x = fmaf(w0, v0.x, fmaf(w1, v1.x, acc[y].x));
            acc[y].y = fmaf(w0, v0.y, fmaf(w1, v1.y, acc[y].y));
            acc[y].z = fmaf(w0, v0.z, fmaf(w1, v1.z, acc[y].z));
            acc[y].w = fmaf(w0, v0.w, fmaf(w1, v1.w, acc[y].w));
            ub += cc;
        }
    }

    #pragma unroll
    for (int y = 0; y < 4; ++y) {
        __syncthreads();
        ob[(zq * 4 + 0) * 33 + xs] = acc[y].x;
        ob[(zq * 4 + 1) * 33 + xs] = acc[y].y;
        ob[(zq * 4 + 2) * 33 + xs] = acc[y].z;
        ob[(zq * 4 + 3) * 33 + xs] = acc[y].w;
        __syncthreads();
        int z  = tid >> 3;
        int x4 = (tid & 7) * 4;
        float4 o = make_float4(ob[z * 33 + x4],     ob[z * 33 + x4 + 1],
                               ob[z * 33 + x4 + 2], ob[z * 33 + x4 + 3]);
        *(float4*)(out + (size_t)z * (NY * NX) + (yb + y) * NX + xb + x4) =
            make_float4(-LAMB * o.x, -LAMB * o.y, -LAMB * o.z, -LAMB * o.w);
    }
}

// ---------------------------------------------------------------------------
extern "C" void kernel_launch(void* const* d_in, const int* in_sizes, int n_in,
                              void* d_out, int out_size, void* d_ws, size_t ws_size,
                              hipStream_t stream) {
    const float* x = (const float*)d_in[0];   // (1,1,32,256,256)
    const float* p = (const float*)d_in[1];   // (1,1,384,8,256)
    float* out = (float*)d_out;               // (1,1,32,256,256)
    float* ws  = (float*)d_ws;

    float*          trig  = ws + TRIG_OFF;
    float*          res_t = ws + REST_OFF;
    unsigned short* vol_b = (unsigned short*)(ws + VOLB_OFF);
    float*          part  = ws + PART_OFF;

    // pair count (expect 2); halve if ws too small
    size_t avail = ws_size / 4;
    int P = 2;
    while (P > 1 && (size_t)PART_OFF + (size_t)P * RES_ELEMS > avail) P >>= 1;

    k_transpose<<<dim3(NX / 64, NY), 256, 0, stream>>>(x, vol_b, trig);
    k_forward  <<<dim3(4 * P * A), 256, 0, stream>>>(vol_b, trig, part, P);
    k_combine  <<<dim3(A, 4), 256, 0, stream>>>(p, part, res_t, P);
    k_backward <<<dim3(NX / 32, NY / 4), 256, 0, stream>>>(res_t, trig, out);
}

// Round 9
// 225.893 us; speedup vs baseline: 1.1493x; 1.0519x over previous
//
#include <hip/hip_runtime.h>

#define A     96
#define DET0  256
#define NZ    32
#define NY    256
#define NX    256
#define T     256
#define LAMB  0.01f

// ws layout (floats):
//   trig  : [A][2]            @ 0        (192, padded to 256)
//   res_t : [A][DET0][NZ]     @ 256      (786,432)
//   vol_b : [NY][NX][NZ] bf16 @ 786,688  (2,097,152 ushort = 1,048,576 floats)
//   part  : [C][A][DET0][NZ]  @ 1,835,264  (C <= 8 -> up to 6,291,456 floats)
#define TRIG_OFF  0
#define REST_OFF  256
#define VOLB_OFF  786688
#define PART_OFF  1835264
#define RES_ELEMS 786432

__device__ __forceinline__ unsigned short f2bf_rne(float f) {
    unsigned u = __float_as_uint(f);
    unsigned r = u + 0x7FFF + ((u >> 16) & 1);
    return (unsigned short)(r >> 16);
}
__device__ __forceinline__ float blo(unsigned u) { return __uint_as_float(u << 16); }
__device__ __forceinline__ float bhi(unsigned u) { return __uint_as_float(u & 0xFFFF0000u); }

// accumulate 8 bf16 * w into acc[0..7]
__device__ __forceinline__ void acc8(float* acc, uint4 q, float w) {
    acc[0] = fmaf(w, blo(q.x), acc[0]); acc[1] = fmaf(w, bhi(q.x), acc[1]);
    acc[2] = fmaf(w, blo(q.y), acc[2]); acc[3] = fmaf(w, bhi(q.y), acc[3]);
    acc[4] = fmaf(w, blo(q.z), acc[4]); acc[5] = fmaf(w, bhi(q.z), acc[5]);
    acc[6] = fmaf(w, blo(q.w), acc[6]); acc[7] = fmaf(w, bhi(q.w), acc[7]);
}
// accumulate 16 bf16 (32 B at p0) * w into acc[0..15]
__device__ __forceinline__ void acc16(float* acc, const char* p0, float w) {
    acc8(acc,     *(const uint4*)p0,        w);
    acc8(acc + 8, *(const uint4*)(p0 + 16), w);
}

// ---------------------------------------------------------------------------
// K1: transpose vol (z,y,x) fp32 -> vol_b (y,x,z) bf16; fill trig table.
// grid (NX/64, NY), block 256
__global__ __launch_bounds__(256) void k_transpose(const float* __restrict__ src,
                                                   unsigned short* __restrict__ vol_b,
                                                   float* __restrict__ trig) {
    __shared__ float lds[64 * 33];
    const int y   = blockIdx.y;
    const int x0  = blockIdx.x * 64;
    const int tid = threadIdx.x;

    if (blockIdx.x == 0 && y == 0 && tid < A) {
        float th = (float)tid * (float)(3.14159265358979323846 / (double)A);
        trig[2 * tid]     = cosf(th);
        trig[2 * tid + 1] = sinf(th);
    }

    const int xr = tid & 63;
    const int zr = tid >> 6;  // 0..3
    #pragma unroll
    for (int pz = 0; pz < 8; ++pz) {
        int z = pz * 4 + zr;
        lds[xr * 33 + z] = src[(z * NY + y) * NX + x0 + xr];
    }
    __syncthreads();
    const int zw = tid & 31;
    const int xw = tid >> 5;  // 0..7
    #pragma unroll
    for (int px = 0; px < 8; ++px) {
        int xi = px * 8 + xw;
        vol_b[(y * NX + x0 + xi) * NZ + zw] = f2bf_rne(lds[xi * 33 + zw]);
    }
}

// ---------------------------------------------------------------------------
// t-range helper: solve L <= t*g + b <= H for t (tt = t - 127.5 domain)
__device__ __forceinline__ void rng(float g, float b, float L, float H,
                                    float& lo, float& hi) {
    if (fabsf(g) > 1e-5f) {
        float r0 = (L - b) / g, r1 = (H - b) / g;
        lo = fminf(r0, r1); hi = fmaxf(r0, r1);
    } else {
        bool in = (b >= L && b <= H);
        lo = in ? -1e9f : 1e9f;
        hi = in ? 1e9f : -1e9f;
    }
}
__device__ __forceinline__ int clampi(float v) {
    return (int)fminf(fmaxf(v, -2.f), 258.f);
}

// fully-masked edge sample (boundary t's), 16 z per lane
__device__ __forceinline__ void sample_edge(const char* base, float ix, float iy,
                                            float* acc) {
    float xf = floorf(ix), yf = floorf(iy);
    float fx = ix - xf, fy = iy - yf;
    int x0 = (int)xf, y0 = (int)yf;
    float wx0 = 1.f - fx, wx1 = fx, wy0 = 1.f - fy, wy1 = fy;
    if ((unsigned)x0 >= NX)       wx0 = 0.f;
    if ((unsigned)(x0 + 1) >= NX) wx1 = 0.f;
    if ((unsigned)y0 >= NY)       wy0 = 0.f;
    if ((unsigned)(y0 + 1) >= NY) wy1 = 0.f;
    if ((wx0 == 0.f && wx1 == 0.f) || (wy0 == 0.f && wy1 == 0.f)) return;
    int cx0 = min(max(x0, 0), NX - 1);
    int cx1 = min(max(x0 + 1, 0), NX - 1);
    int cy0 = min(max(y0, 0), NY - 1);
    int cy1 = min(max(y0 + 1, 0), NY - 1);
    acc16(acc, base + ((size_t)((cy0 << 8) + cx0) << 6), wy0 * wx0);
    acc16(acc, base + ((size_t)((cy0 << 8) + cx1) << 6), wy0 * wx1);
    acc16(acc, base + ((size_t)((cy1 << 8) + cx0) << 6), wy1 * wx0);
    acc16(acc, base + ((size_t)((cy1 << 8) + cx1) << 6), wy1 * wx1);
}

// ---------------------------------------------------------------------------
// K3: forward projection, bf16 volume. thread = (u, z-half), 16 z per lane.
// Per-u fractional chunking: chunk ci covers exactly 1/C of this u's own
// valid t-range (clamped to the t grid [0,255]!) -> balanced blocks.
// grid (2 * C * A), block 256 (128 u x 2 z-halves)
__global__ __launch_bounds__(256) void k_forward(const unsigned short* __restrict__ vol_b,
                                                 const float* __restrict__ trig,
                                                 float* __restrict__ part,
                                                 int C) {
    const int bid = blockIdx.x;
    const int a   = bid % A;
    const int r   = bid / A;
    const int ci  = r % C;
    const int ug  = r / C;            // 0..1
    const int tid = threadIdx.x;
    const int ul  = tid >> 1;         // 0..127
    const int zh  = tid & 1;          // 16 bf16 z per lane = 32 bytes
    const int u   = ug * 128 + ul;

    const float c = trig[2 * a];
    const float s = trig[2 * a + 1];
    const float uu = (float)u - 127.5f;
    const float bx = fmaf(-uu, s, 127.5f);  // ix = tt*c + bx
    const float by = fmaf(uu, c, 127.5f);   // iy = tt*s + by

    // full valid range and strict-interior range for this u
    float lo1, hi1, lo2, hi2;
    rng(c, bx, -1.f, 256.f, lo1, hi1);
    rng(s, by, -1.f, 256.f, lo2, hi2);
    float fl = fmaxf(lo1, lo2), fh = fminf(hi1, hi2);
    int gF0 = clampi(ceilf(fl + 127.5f));
    int gF1 = clampi(floorf(fh + 127.5f));
    gF0 = max(gF0, 0);            // FIX: restrict to the t sample grid
    gF1 = min(gF1, T - 1);
    rng(c, bx, 1.f, 253.5f, lo1, hi1);
    rng(s, by, 1.f, 253.5f, lo2, hi2);
    float il = fmaxf(lo1, lo2), ih = fminf(hi1, hi2);
    const int gI0 = clampi(ceilf(il + 127.5f)) + 1;
    const int gI1 = clampi(floorf(ih + 127.5f)) - 1;

    // this chunk's slice of the valid range
    const int len = max(0, gF1 - gF0 + 1);
    const int q0  = gF0 + (len * ci) / C;
    const int q1  = gF0 + (len * (ci + 1)) / C;

    const char* base = (const char*)vol_b + zh * 32;
    float acc[16];
    #pragma unroll
    for (int k = 0; k < 16; ++k) acc[k] = 0.f;

    // head edge samples (only first chunk typically has any)
    const int hE = min(q1, gI0);
    for (int t = q0; t < hE; ++t) {
        float ttf = (float)t - 127.5f;
        sample_edge(base, fmaf(ttf, c, bx), fmaf(ttf, s, by), acc);
    }
    // interior (mask-free)
    const int i0 = max(q0, gI0), i1 = min(q1, gI1 + 1);
    for (int t = i0; t < i1; ++t) {
        float ttf = (float)t - 127.5f;
        float ix = fmaf(ttf, c, bx);
        float iy = fmaf(ttf, s, by);
        float xf = floorf(ix), yf = floorf(iy);
        float fx = ix - xf, fy = iy - yf;
        int row = ((int)yf << 8) + (int)xf;
        const char* p0 = base + ((size_t)row << 6);
        float wx0 = 1.f - fx, wy0 = 1.f - fy;
        acc16(acc, p0,               wy0 * wx0);
        acc16(acc, p0 + 64,          wy0 * fx);
        acc16(acc, p0 + 16384,       fy * wx0);
        acc16(acc, p0 + 16384 + 64,  fy * fx);
    }
    // tail edge samples (only last chunk typically has any)
    const int t2 = max(max(q0, gI1 + 1), hE);
    for (int t = t2; t < q1; ++t) {
        float ttf = (float)t - 127.5f;
        sample_edge(base, fmaf(ttf, c, bx), fmaf(ttf, s, by), acc);
    }

    float4* dst = (float4*)(part + (size_t)ci * RES_ELEMS +
                            ((a * DET0 + u) * NZ + zh * 16));
    dst[0] = make_float4(acc[0],  acc[1],  acc[2],  acc[3]);
    dst[1] = make_float4(acc[4],  acc[5],  acc[6],  acc[7]);
    dst[2] = make_float4(acc[8],  acc[9],  acc[10], acc[11]);
    dst[3] = make_float4(acc[12], acc[13], acc[14], acc[15]);
}

// ---------------------------------------------------------------------------
// K3b: res_t = -p_perm + sum_c part[c].  grid (A, 4), block 256
__global__ __launch_bounds__(256) void k_combine(const float* __restrict__ p,
                                                 const float* __restrict__ part,
                                                 float* __restrict__ res_t,
                                                 int C) {
    __shared__ float lds[64 * 33];
    const int a  = blockIdx.x;
    const int uq = blockIdx.y;
    const int tid = threadIdx.x;
    #pragma unroll
    for (int k = 0; k < 8; ++k) {
        int e  = k * 256 + tid;  // 0..2047
        int uo = e & 63;
        int z  = e >> 6;
        int pidx = a * 8192 + (((z & 7) << 2) + (z >> 3)) * 256 + uq * 64 + uo;
        lds[uo * 33 + z] = p[pidx];
    }
    __syncthreads();
    #pragma unroll
    for (int k = 0; k < 2; ++k) {
        int j4 = k * 256 + tid;          // float4 index within (a,uq)
        int uo = j4 >> 3;
        int zb = (j4 & 7) * 4;
        float4 v = make_float4(-lds[uo * 33 + zb],     -lds[uo * 33 + zb + 1],
                               -lds[uo * 33 + zb + 2], -lds[uo * 33 + zb + 3]);
        size_t gi = (size_t)a * 2048 + uq * 512 + j4;
        for (int c = 0; c < C; ++c) {
            float4 w = ((const float4*)(part + (size_t)c * RES_ELEMS))[gi];
            v.x += w.x; v.y += w.y; v.z += w.z; v.w += w.w;
        }
        ((float4*)res_t)[gi] = v;
    }
}

// ---------------------------------------------------------------------------
// K4: backprojection, y-tiled x4. thread = (x, z-quarter of 4), 4 y-accums.
// grid (NX/32, NY/4), block 256
__global__ __launch_bounds__(256) void k_backward(const float* __restrict__ res_t,
                                                  const float* __restrict__ trig,
                                                  float* __restrict__ out) {
    __shared__ float ob[32 * 33];
    const int tid = threadIdx.x;
    const int xs = tid >> 3;         // 0..31
    const int zq = tid & 7;          // 4 z per lane
    const int xb = blockIdx.x * 32;
    const int yb = blockIdx.y * 4;
    const float xx = (float)(xb + xs) - 127.5f;
    const float yy = (float)yb - 127.5f;

    float4 acc[4];
    #pragma unroll
    for (int k = 0; k < 4; ++k) acc[k] = make_float4(0.f, 0.f, 0.f, 0.f);

    const char* rbase = (const char*)res_t + zq * 16;
    for (int a = 0; a < A; ++a) {
        float cc = trig[2 * a];
        float ss = trig[2 * a + 1];
        float ub = fmaf(-xx, ss, fmaf(yy, cc, 127.5f));
        int abase = a * DET0;
        #pragma unroll
        for (int y = 0; y < 4; ++y) {
            float uf = floorf(ub);
            float fu = ub - uf;
            int i0 = (int)uf;
            float w0 = ((unsigned)i0 < 256u) ? (1.f - fu) : 0.f;
            float w1 = ((unsigned)(i0 + 1) < 256u) ? fu : 0.f;
            int c0 = min(max(i0, 0), 255);
            int c1 = min(max(i0 + 1, 0), 255);
            float4 v0 = *(const float4*)(rbase + ((size_t)(abase + c0) << 7));
            float4 v1 = *(const float4*)(rbase + ((size_t)(abase + c1) << 7));
            acc[y].x = fmaf(w0, v0.x, fmaf(w1, v1.x, acc[y].x));
            acc[y].y = fmaf(w0, v0.y, fmaf(w1, v1.y, acc[y].y));
            acc[y].z = fmaf(w0, v0.z, fmaf(w1, v1.z, acc[y].z));
            acc[y].w = fmaf(w0, v0.w, fmaf(w1, v1.w, acc[y].w));
            ub += cc;
        }
    }

    #pragma unroll
    for (int y = 0; y < 4; ++y) {
        __syncthreads();
        ob[(zq * 4 + 0) * 33 + xs] = acc[y].x;
        ob[(zq * 4 + 1) * 33 + xs] = acc[y].y;
        ob[(zq * 4 + 2) * 33 + xs] = acc[y].z;
        ob[(zq * 4 + 3) * 33 + xs] = acc[y].w;
        __syncthreads();
        int z  = tid >> 3;
        int x4 = (tid & 7) * 4;
        float4 o = make_float4(ob[z * 33 + x4],     ob[z * 33 + x4 + 1],
                               ob[z * 33 + x4 + 2], ob[z * 33 + x4 + 3]);
        *(float4*)(out + (size_t)z * (NY * NX) + (yb + y) * NX + xb + x4) =
            make_float4(-LAMB * o.x, -LAMB * o.y, -LAMB * o.z, -LAMB * o.w);
    }
}

// ---------------------------------------------------------------------------
extern "C" void kernel_launch(void* const* d_in, const int* in_sizes, int n_in,
                              void* d_out, int out_size, void* d_ws, size_t ws_size,
                              hipStream_t stream) {
    const float* x = (const float*)d_in[0];   // (1,1,32,256,256)
    const float* p = (const float*)d_in[1];   // (1,1,384,8,256)
    float* out = (float*)d_out;               // (1,1,32,256,256)
    float* ws  = (float*)d_ws;

    float*          trig  = ws + TRIG_OFF;
    float*          res_t = ws + REST_OFF;
    unsigned short* vol_b = (unsigned short*)(ws + VOLB_OFF);
    float*          part  = ws + PART_OFF;

    // largest chunk count (<=8) whose partials fit in ws (expect 8)
    size_t avail = ws_size / 4;
    int C = 8;
    while (C > 1 && (size_t)PART_OFF + (size_t)C * RES_ELEMS > avail) C >>= 1;

    k_transpose<<<dim3(NX / 64, NY), 256, 0, stream>>>(x, vol_b, trig);
    k_forward  <<<dim3(2 * C * A), 256, 0, stream>>>(vol_b, trig, part, C);
    k_combine  <<<dim3(A, 4), 256, 0, stream>>>(p, part, res_t, C);
    k_backward <<<dim3(NX / 32, NY / 4), 256, 0, stream>>>(res_t, trig, out);
}